// Round 10
// baseline (83.852 us; speedup 1.0000x reference)
//
#include <hip/hip_runtime.h>
#include <hip/hip_bf16.h>

#define TPB 256
#define NEXPERT 64

typedef float f32x4 __attribute__((ext_vector_type(4)));

// ---------------------------------------------------------------------------
// R10 = R8 with hist+scatter fused via a 64-block grid barrier (prelude only;
// gather keeps its own 8192-block dispatch — R5's failure was starving the
// gather, not the barrier, which validated correct).
// Phase A: own-chunk 64-bin hist (R8's proven atomicAdd form) -> counts.
// Barrier: device-scope acq_rel counter among NB blocks (co-resident since
//          NB=64 <= 256 CUs); bounded spin as safety valve.
// Phase B: bulk-load all counts (16 KB coalesced), R8-proven LDS exclusive
//          scan, R8-proven ballot stable rank, write outputs.
// ---------------------------------------------------------------------------
__global__ __launch_bounds__(TPB) void k_prelude_bar(
    const int* __restrict__ expert, const int* __restrict__ rowi,
    int NK, int NB, unsigned* __restrict__ bar, int* __restrict__ counts,
    float* __restrict__ out_row, float* __restrict__ out_expert,
    int* __restrict__ dst_of_r) {
    extern __shared__ int lds[];             // [M] counts | [TPB] scan temp
    __shared__ int h64[NEXPERT];
    __shared__ int hw[TPB / 64][NEXPERT + 1];
    const int M = NEXPERT * NB;
    int* cnt = lds;
    int* s = lds + M;
    const int b = blockIdx.x;
    const int tid = threadIdx.x;
    const int w = tid >> 6;
    const int lane = tid & 63;

    // ---- Phase A: own-chunk histogram (R8's k_hist, verbatim logic) ----
    if (tid < NEXPERT) h64[tid] = 0;
    __syncthreads();
    const int i = b * TPB + tid;
    const bool valid = (i < NK);
    const int e = valid ? expert[i] : NEXPERT;   // sentinel for inactive lanes
    if (valid) atomicAdd(&h64[e], 1);
    __syncthreads();
    if (tid < NEXPERT) counts[tid * NB + b] = h64[tid];

    // ---- grid barrier over NB co-resident blocks ----
    __threadfence();                         // order counts writes (device)
    __syncthreads();
    if (tid == 0) {
        __hip_atomic_fetch_add(bar, 1u, __ATOMIC_ACQ_REL,
                               __HIP_MEMORY_SCOPE_AGENT);
        long long guard = 0;
        while (__hip_atomic_load(bar, __ATOMIC_ACQUIRE,
                                 __HIP_MEMORY_SCOPE_AGENT) < (unsigned)NB) {
            __builtin_amdgcn_s_sleep(2);
            if (++guard > (1LL << 22)) break;  // safety valve: fail, not hang
        }
    }
    __syncthreads();

    // ---- Phase B: bulk-load counts + exclusive scan in LDS (R8-proven) ----
    for (int j = tid; j < M; j += TPB) cnt[j] = counts[j];
    for (int idx = tid; idx < (TPB / 64) * (NEXPERT + 1); idx += TPB)
        (&hw[0][0])[idx] = 0;
    __syncthreads();

    const int ipt = (M + TPB - 1) / TPB;     // 16 for the 8192x4096 shape
    const int base_i = tid * ipt;
    int sum = 0;
    for (int j = 0; j < ipt; ++j) sum += (base_i + j < M) ? cnt[base_i + j] : 0;
    s[tid] = sum;
    __syncthreads();
    for (int off = 1; off < TPB; off <<= 1) {
        const int xv = (tid >= off) ? s[tid - off] : 0;
        __syncthreads();
        s[tid] += xv;
        __syncthreads();
    }
    int run = (tid == 0) ? 0 : s[tid - 1];
    for (int j = 0; j < ipt; ++j) {
        if (base_i + j < M) {
            const int c = cnt[base_i + j];
            cnt[base_i + j] = run;
            run += c;
        }
    }
    __syncthreads();

    // ---- ballot-based stable rank (byte-identical to R2/R8) ----
    unsigned long long mask = ~0ull;
#pragma unroll
    for (int bit = 0; bit < 7; ++bit) {
        const unsigned long long bv = __ballot((e >> bit) & 1);
        mask &= ((e >> bit) & 1) ? bv : ~bv;
    }
    const int rank_w = __popcll(mask & ((1ull << lane) - 1ull));
    const int cnt_w  = __popcll(mask);
    if (rank_w == 0) hw[w][e] = cnt_w;   // lowest lane of each expert group
    __syncthreads();

    if (valid) {
        int rank = rank_w;
        for (int w2 = 0; w2 < w; ++w2) rank += hw[w2][e];
        const int dst = cnt[e * NB + b] + rank;
        const int r = rowi[i];
        out_expert[dst] = (float)e;
        out_row[r] = (float)dst;
        dst_of_r[r] = dst;
    }
}

// ---------------------------------------------------------------------------
// Fallback prelude (R8's two kernels) for NB > 256 where co-residency of the
// barrier grid isn't guaranteed. Not used at the bench shape (NB = 64).
// ---------------------------------------------------------------------------
__global__ void k_hist(const int* __restrict__ expert, int NK, int NB,
                       int* __restrict__ counts) {
    __shared__ int h[NEXPERT];
    const int b = blockIdx.x;
    for (int e = threadIdx.x; e < NEXPERT; e += blockDim.x) h[e] = 0;
    __syncthreads();
    const int i = b * TPB + threadIdx.x;
    if (i < NK) atomicAdd(&h[expert[i]], 1);
    __syncthreads();
    for (int e = threadIdx.x; e < NEXPERT; e += blockDim.x)
        counts[e * NB + b] = h[e];
}

__global__ __launch_bounds__(TPB) void k_scatter(
    const int* __restrict__ expert, const int* __restrict__ rowi,
    int NK, int NB, const int* __restrict__ counts,
    float* __restrict__ out_row, float* __restrict__ out_expert,
    int* __restrict__ dst_of_r) {
    extern __shared__ int lds[];
    __shared__ int h[TPB / 64][NEXPERT + 1];
    const int M = NEXPERT * NB;
    int* cnt = lds;
    int* s = lds + M;
    const int b = blockIdx.x;
    const int tid = threadIdx.x;
    const int w = tid >> 6;
    const int lane = tid & 63;

    for (int j = tid; j < M; j += TPB) cnt[j] = counts[j];
    for (int idx = tid; idx < (TPB / 64) * (NEXPERT + 1); idx += TPB)
        (&h[0][0])[idx] = 0;
    __syncthreads();

    const int ipt = (M + TPB - 1) / TPB;
    const int base_i = tid * ipt;
    int sum = 0;
    for (int j = 0; j < ipt; ++j) sum += (base_i + j < M) ? cnt[base_i + j] : 0;
    s[tid] = sum;
    __syncthreads();
    for (int off = 1; off < TPB; off <<= 1) {
        const int xv = (tid >= off) ? s[tid - off] : 0;
        __syncthreads();
        s[tid] += xv;
        __syncthreads();
    }
    int run = (tid == 0) ? 0 : s[tid - 1];
    for (int j = 0; j < ipt; ++j) {
        if (base_i + j < M) {
            const int c = cnt[base_i + j];
            cnt[base_i + j] = run;
            run += c;
        }
    }
    __syncthreads();

    const int i = b * TPB + tid;
    const bool valid = (i < NK);
    const int e = valid ? expert[i] : NEXPERT;

    unsigned long long mask = ~0ull;
#pragma unroll
    for (int bit = 0; bit < 7; ++bit) {
        const unsigned long long bv = __ballot((e >> bit) & 1);
        mask &= ((e >> bit) & 1) ? bv : ~bv;
    }
    const int rank_w = __popcll(mask & ((1ull << lane) - 1ull));
    const int cnt_w  = __popcll(mask);
    if (rank_w == 0) h[w][e] = cnt_w;
    __syncthreads();

    if (valid) {
        int rank = rank_w;
        for (int w2 = 0; w2 < w; ++w2) rank += h[w2][e];
        const int dst = cnt[e * NB + b] + rank;
        const int r = rowi[i];
        out_expert[dst] = (float)e;
        out_row[r] = (float)dst;
        dst_of_r[r] = dst;
    }
}

// K: token-driven gather (byte-identical to R2/R8's validated winner).
template <int K>
__global__ void k_gatherT(const float* __restrict__ x,
                          const int* __restrict__ dst_of_r,
                          float* __restrict__ out_x, int H, int N) {
    const int t = blockIdx.x;
    const f32x4* __restrict__ src = (const f32x4*)(x + (size_t)t * (size_t)H);
    size_t ob[K];
#pragma unroll
    for (int kk = 0; kk < K; ++kk)
        ob[kk] = (size_t)dst_of_r[t + kk * N] * (size_t)H;
    const int n4 = H >> 2;
    for (int j = threadIdx.x; j < n4; j += blockDim.x) {
        const f32x4 v = src[j];
#pragma unroll
        for (int kk = 0; kk < K; ++kk)
            __builtin_nontemporal_store(v, (f32x4*)(out_x + ob[kk]) + j);
    }
}

// Generic-K fallback (only used for K > 4)
__global__ void k_gather_gen(const float* __restrict__ x,
                             const int* __restrict__ dst_of_r,
                             float* __restrict__ out_x, int H, int N, int K) {
    const int t = blockIdx.x;
    const f32x4* __restrict__ src = (const f32x4*)(x + (size_t)t * (size_t)H);
    const int n4 = H >> 2;
    for (int kk = 0; kk < K; ++kk) {
        const size_t ob = (size_t)dst_of_r[t + kk * N] * (size_t)H;
        for (int j = threadIdx.x; j < n4; j += blockDim.x)
            __builtin_nontemporal_store(src[j], (f32x4*)(out_x + ob) + j);
    }
}

extern "C" void kernel_launch(void* const* d_in, const int* in_sizes, int n_in,
                              void* d_out, int out_size, void* d_ws, size_t ws_size,
                              hipStream_t stream) {
    const float* x    = (const float*)d_in[0];  // [N, H] fp32
    const int*   rowi = (const int*)d_in[1];    // [N, K] int32 (arange)
    const int*   expi = (const int*)d_in[2];    // [N, K] int32

    const int NK = in_sizes[1];                    // N*K = 16384
    const int H  = (out_size - 2 * NK) / NK;       // 4096
    const int N  = in_sizes[0] / H;                // 8192
    const int K  = NK / N;                         // 2
    const int NB = (NK + TPB - 1) / TPB;           // 64 chunks

    // Output layout (all float32): [NK*H] expanded_x | [NK] row_idx | [NK] expert_idx
    float* out_x      = (float*)d_out;
    float* out_row    = out_x + (size_t)NK * (size_t)H;
    float* out_expert = out_row + NK;

    // Workspace: [0] barrier | +64 ints: counts [64*NB] | dst_of_r [NK]
    unsigned* bar = (unsigned*)d_ws;
    int* counts   = (int*)d_ws + 64;
    int* dst_of_r = counts + NEXPERT * NB;

    const int M = NEXPERT * NB;
    const size_t lds_bytes = (size_t)(M + TPB) * sizeof(int);

    if (NB <= 256) {
        hipMemsetAsync(bar, 0, sizeof(unsigned), stream);
        k_prelude_bar<<<NB, TPB, lds_bytes, stream>>>(
            expi, rowi, NK, NB, bar, counts, out_row, out_expert, dst_of_r);
    } else {
        k_hist   <<<NB, TPB, 0, stream>>>(expi, NK, NB, counts);
        k_scatter<<<NB, TPB, lds_bytes, stream>>>(expi, rowi, NK, NB, counts,
                                                  out_row, out_expert, dst_of_r);
    }

    switch (K) {
        case 1: k_gatherT<1><<<N, TPB, 0, stream>>>(x, dst_of_r, out_x, H, N); break;
        case 2: k_gatherT<2><<<N, TPB, 0, stream>>>(x, dst_of_r, out_x, H, N); break;
        case 3: k_gatherT<3><<<N, TPB, 0, stream>>>(x, dst_of_r, out_x, H, N); break;
        case 4: k_gatherT<4><<<N, TPB, 0, stream>>>(x, dst_of_r, out_x, H, N); break;
        default: k_gather_gen<<<N, TPB, 0, stream>>>(x, dst_of_r, out_x, H, N, K); break;
    }
}

// Round 11
// 75.444 us; speedup vs baseline: 1.1115x; 1.1115x over previous
//
#include <hip/hip_runtime.h>
#include <hip/hip_bf16.h>

#define TPB 256
#define NEXPERT 64

typedef float f32x4 __attribute__((ext_vector_type(4)));

// ---------------------------------------------------------------------------
// FINAL = R8 (75.3 µs, best of 10 rounds): 3 dispatches.
//   k_hist    : per-chunk 64-bin histogram -> counts[e*NB + b]
//   k_scatter : per-block redundant LDS scan of counts + ballot stable rank
//   k_gatherT : token-driven gather, plain loads + NT float4 stores
// Fusion variants (single-block, grid-barrier, redundant-hist) all measured
// slower; launch gaps are cheaper than any on-chip alternative here.
// ---------------------------------------------------------------------------

// K1: per-chunk expert histogram. counts[e * NB + b] layout (raw counts).
__global__ void k_hist(const int* __restrict__ expert, int NK, int NB,
                       int* __restrict__ counts) {
    __shared__ int h[NEXPERT];
    const int b = blockIdx.x;
    for (int e = threadIdx.x; e < NEXPERT; e += blockDim.x) h[e] = 0;
    __syncthreads();
    const int i = b * TPB + threadIdx.x;
    if (i < NK) atomicAdd(&h[expert[i]], 1);
    __syncthreads();
    for (int e = threadIdx.x; e < NEXPERT; e += blockDim.x)
        counts[e * NB + b] = h[e];
}

// K2: stable scatter with in-block redundant scan + ballot rank.
__global__ __launch_bounds__(TPB) void k_scatter(
    const int* __restrict__ expert, const int* __restrict__ rowi,
    int NK, int NB, const int* __restrict__ counts,
    float* __restrict__ out_row, float* __restrict__ out_expert,
    int* __restrict__ dst_of_r) {
    extern __shared__ int lds[];             // [M] scanned counts | [TPB] s
    __shared__ int h[TPB / 64][NEXPERT + 1];
    const int M = NEXPERT * NB;
    int* cnt = lds;
    int* s = lds + M;
    const int b = blockIdx.x;
    const int tid = threadIdx.x;
    const int w = tid >> 6;
    const int lane = tid & 63;

    // ---- bulk-load raw counts (one coalesced pass, no serial round-trips)
    for (int j = tid; j < M; j += TPB) cnt[j] = counts[j];
    // zero the cross-wave rank table while loads are in flight
    for (int idx = tid; idx < (TPB / 64) * (NEXPERT + 1); idx += TPB)
        (&h[0][0])[idx] = 0;
    __syncthreads();

    // ---- exclusive scan of cnt[0..M) in LDS (ipt consecutive per thread)
    const int ipt = M / TPB;                 // 16 for the 8192x4096 shape
    const int base_i = tid * ipt;
    int sum = 0;
    for (int j = 0; j < ipt; ++j) sum += cnt[base_i + j];
    s[tid] = sum;
    __syncthreads();
    for (int off = 1; off < TPB; off <<= 1) {
        const int xv = (tid >= off) ? s[tid - off] : 0;
        __syncthreads();
        s[tid] += xv;
        __syncthreads();
    }
    int run = (tid == 0) ? 0 : s[tid - 1];
    for (int j = 0; j < ipt; ++j) {
        const int c = cnt[base_i + j];
        cnt[base_i + j] = run;
        run += c;
    }
    __syncthreads();

    // ---- ballot-based stable rank ----
    const int i = b * TPB + tid;
    const bool valid = (i < NK);
    const int e = valid ? expert[i] : NEXPERT;   // sentinel for inactive lanes

    unsigned long long mask = ~0ull;
#pragma unroll
    for (int bit = 0; bit < 7; ++bit) {
        const unsigned long long bv = __ballot((e >> bit) & 1);
        mask &= ((e >> bit) & 1) ? bv : ~bv;
    }
    const int rank_w = __popcll(mask & ((1ull << lane) - 1ull));
    const int cnt_w  = __popcll(mask);
    if (rank_w == 0) h[w][e] = cnt_w;   // lowest lane of each expert group
    __syncthreads();

    if (valid) {
        int rank = rank_w;
        for (int w2 = 0; w2 < w; ++w2) rank += h[w2][e];
        const int dst = cnt[e * NB + b] + rank;
        const int r = rowi[i];
        out_expert[dst] = (float)e;
        out_row[r] = (float)dst;
        dst_of_r[r] = dst;
    }
}

// K3: token-driven gather. Token t is consumed by exactly the row VALUES
// {t, t+N, ...} (reference gathers x[r % N]; row values are arange). Read
// x[t] ONCE (plain loads — x is ~50% L3-resident), write to all K
// destinations with nontemporal float4 stores.
template <int K>
__global__ void k_gatherT(const float* __restrict__ x,
                          const int* __restrict__ dst_of_r,
                          float* __restrict__ out_x, int H, int N) {
    const int t = blockIdx.x;
    const f32x4* __restrict__ src = (const f32x4*)(x + (size_t)t * (size_t)H);
    size_t ob[K];
#pragma unroll
    for (int kk = 0; kk < K; ++kk)
        ob[kk] = (size_t)dst_of_r[t + kk * N] * (size_t)H;
    const int n4 = H >> 2;
    for (int j = threadIdx.x; j < n4; j += blockDim.x) {
        const f32x4 v = src[j];
#pragma unroll
        for (int kk = 0; kk < K; ++kk)
            __builtin_nontemporal_store(v, (f32x4*)(out_x + ob[kk]) + j);
    }
}

// Generic-K fallback (only used for K > 4)
__global__ void k_gather_gen(const float* __restrict__ x,
                             const int* __restrict__ dst_of_r,
                             float* __restrict__ out_x, int H, int N, int K) {
    const int t = blockIdx.x;
    const f32x4* __restrict__ src = (const f32x4*)(x + (size_t)t * (size_t)H);
    const int n4 = H >> 2;
    for (int kk = 0; kk < K; ++kk) {
        const size_t ob = (size_t)dst_of_r[t + kk * N] * (size_t)H;
        for (int j = threadIdx.x; j < n4; j += blockDim.x)
            __builtin_nontemporal_store(src[j], (f32x4*)(out_x + ob) + j);
    }
}

extern "C" void kernel_launch(void* const* d_in, const int* in_sizes, int n_in,
                              void* d_out, int out_size, void* d_ws, size_t ws_size,
                              hipStream_t stream) {
    const float* x    = (const float*)d_in[0];  // [N, H] fp32
    const int*   rowi = (const int*)d_in[1];    // [N, K] int32 (arange)
    const int*   expi = (const int*)d_in[2];    // [N, K] int32

    const int NK = in_sizes[1];                    // N*K = 16384
    const int H  = (out_size - 2 * NK) / NK;       // 4096
    const int N  = in_sizes[0] / H;                // 8192
    const int K  = NK / N;                         // 2
    const int NB = (NK + TPB - 1) / TPB;           // 64 chunks

    // Output layout (all float32): [NK*H] expanded_x | [NK] row_idx | [NK] expert_idx
    float* out_x      = (float*)d_out;
    float* out_row    = out_x + (size_t)NK * (size_t)H;
    float* out_expert = out_row + NK;

    // Workspace: raw counts [64*NB] ints, then dst_of_r [NK] ints.
    int* counts   = (int*)d_ws;
    int* dst_of_r = counts + NEXPERT * NB;

    const int M = NEXPERT * NB;
    const size_t lds_bytes = (size_t)(M + TPB) * sizeof(int);

    k_hist   <<<NB, TPB, 0, stream>>>(expi, NK, NB, counts);
    k_scatter<<<NB, TPB, lds_bytes, stream>>>(expi, rowi, NK, NB, counts,
                                              out_row, out_expert, dst_of_r);

    switch (K) {
        case 1: k_gatherT<1><<<N, TPB, 0, stream>>>(x, dst_of_r, out_x, H, N); break;
        case 2: k_gatherT<2><<<N, TPB, 0, stream>>>(x, dst_of_r, out_x, H, N); break;
        case 3: k_gatherT<3><<<N, TPB, 0, stream>>>(x, dst_of_r, out_x, H, N); break;
        case 4: k_gatherT<4><<<N, TPB, 0, stream>>>(x, dst_of_r, out_x, H, N); break;
        default: k_gather_gen<<<N, TPB, 0, stream>>>(x, dst_of_r, out_x, H, N, K); break;
    }
}